// Round 8
// baseline (21111.543 us; speedup 1.0000x reference)
//
#include <hip/hip_runtime.h>

// ---------------------------------------------------------------------------
// V11: XCD-local LSTM — batch-parallel groups, L2-coherent exchange, no MALL
// in the per-step loop.
//
// Key insight: the LSTM recurrence is INDEPENDENT PER BATCH. Partition the 64
// sequences into 8 groups of 8, one group per XCD. All cross-WG exchange for
// a group happens among the 32 WGs of one XCD, which share one L2:
//   - producers: plain stores (dirty L2) -> __syncthreads vmcnt drain ->
//     plain flag store (all 32 group flags live in ONE 128B line).
//   - consumers: per-wave sc0 poll (L1-bypass, L2-hit) -> `buffer_inv`
//     (L1-only invalidate, single instr) -> plain cached loads (L2 hits).
//   No agent fence, no L2 invalidate, no MALL round-trip per step.
// Balance guarantee: 256 WGs, LDS 49KB forces 1 WG/CU -> pigeonhole gives
// exactly 32 WGs per XCD. XCD discovered via s_getreg(HW_REG_XCC_ID) [m09],
// rank via one startup agent atomic.
// Startup safety: per-WG agent acquire fence (clears stale cross-launch L2)
// + MALL rendezvous (ready==256) before any L2-local store, so no startup
// invalidate can discard live data. init_ws re-zeros flags/buffers at MALL
// each launch (graph replay safe).
// Worker r of group g: h1-cols [16r,16r+16) (wave mt -> n-tile mt) and
// h2-cols [8r,8r+8) (waves 2,3 -> L1 n-tiles), batches 8g..8g+7 (M=8, padded
// MFMA rows discarded). Per iter i: h1(i) = f(x(i), h1(i-1)) and
// h2(i-1) = f(h1(i-1), h2(i-2)) — both inputs published before this iter's
// single wait; L1 reuses L0's h1 A-fragments (same slot).
// ---------------------------------------------------------------------------

constexpr int BB   = 64;
constexpr int TT   = 1024;
constexpr int DIN  = 256;
constexpr int H0   = 512;
constexpr int H1   = 256;
constexpr int NWG  = 256;
constexpr int NTHR = 256;
constexpr int NKT  = 24;       // K = 768 = 24 tiles of 32
constexpr int GW   = 32;       // workers per group (= WGs per XCD)

typedef _Float16 v8h __attribute__((ext_vector_type(8)));
typedef __fp16   v2p __attribute__((ext_vector_type(2)));
typedef float    v4f __attribute__((ext_vector_type(4)));
typedef unsigned int v4u __attribute__((ext_vector_type(4)));

union U1 { unsigned u; v2p h; };
union U4 { v4u u; v8h h; };

__device__ __forceinline__ unsigned pk2(float a, float b){
  U1 c; c.h = __builtin_amdgcn_cvt_pkrtz(a, b); return c.u;
}
__device__ __forceinline__ float lo16(unsigned u){ U1 c; c.u = u; return (float)c.h[0]; }
__device__ __forceinline__ float hi16(unsigned u){ U1 c; c.u = u; return (float)c.h[1]; }
__device__ __forceinline__ v8h as_h8(v4u u){ U4 c; c.u = u; return c.h; }

__device__ __forceinline__ v4f mfma16(v8h a, v8h b, v4f c){
  return __builtin_amdgcn_mfma_f32_16x16x32_f16(a, b, c, 0, 0, 0);
}

__device__ __forceinline__ float sigf(float v){ return 1.0f / (1.0f + __expf(-v)); }
__device__ __forceinline__ float tanhf_(float v){
  float e = __expf(2.0f * v);
  return 1.0f - 2.0f / (e + 1.0f);     // inf-safe
}

// XCD id: s_getreg(HW_REG_XCC_ID=20, offset 0, size 4)  [measured: learn_hip m09]
__device__ __forceinline__ unsigned xccid(){
  return (unsigned)__builtin_amdgcn_s_getreg(20 | (0 << 6) | (3 << 11)) & 7u;
}

// sc0 load: bypass L1, hit own-XCD L2 (sees dirty lines written by peer CUs)
__device__ __forceinline__ unsigned ld_sc0(const unsigned* p){
  unsigned v;
  asm volatile("global_load_dword %0, %1, off sc0\n\ts_waitcnt vmcnt(0)"
               : "=v"(v) : "v"(p) : "memory");
  return v;
}

// L1-only invalidate (no L2): data exchanged through the shared XCD L2 stays
// valid; only the per-CU vector L1 may hold stale slot lines.
__device__ __forceinline__ void inv_l1(){
  asm volatile("buffer_inv" ::: "memory");
}

// per-wave wait: all 32 group flags >= tgt.  Flags sit in one 128B line of
// the XCD's L2 -> one coalesced sc0 read per probe.  Bounded (fast-fail).
__device__ __forceinline__ void waitflags(const unsigned* f, unsigned tgt, int lane){
  const unsigned* p = f + (lane & 31);
  for (int it = 0; it < (1 << 17); ++it){
    unsigned v = ld_sc0(p);
    if (__all(v >= tgt)) return;
    __builtin_amdgcn_s_sleep(1);
  }
}

__device__ __forceinline__ void acq_fence(){
  __builtin_amdgcn_fence(__ATOMIC_ACQUIRE, "agent");
}

__device__ __forceinline__ void frag_from_pairs(v4u p0, v4u p1, v8h& A, v8h& B){
  v4u ua, ub;
  ua[0] = __builtin_amdgcn_perm(p0[1], p0[0], 0x05040100u);
  ua[1] = __builtin_amdgcn_perm(p0[3], p0[2], 0x05040100u);
  ua[2] = __builtin_amdgcn_perm(p1[1], p1[0], 0x05040100u);
  ua[3] = __builtin_amdgcn_perm(p1[3], p1[2], 0x05040100u);
  ub[0] = __builtin_amdgcn_perm(p0[1], p0[0], 0x07060302u);
  ub[1] = __builtin_amdgcn_perm(p0[3], p0[2], 0x07060302u);
  ub[2] = __builtin_amdgcn_perm(p1[1], p1[0], 0x07060302u);
  ub[3] = __builtin_amdgcn_perm(p1[3], p1[2], 0x07060302u);
  A = as_h8(ua); B = as_h8(ub);
}

__device__ __forceinline__ void frag_from_floats(v4f f0, v4f f1, v8h& A, v8h& B){
  float v[8] = { f0[0], f0[1], f0[2], f0[3], f1[0], f1[1], f1[2], f1[3] };
  v4u ua, ub;
  #pragma unroll
  for (int d = 0; d < 4; ++d){
    unsigned p = pk2(v[2*d], v[2*d+1]);
    ua[d] = p;
    ub[d] = pk2(v[2*d] - lo16(p), v[2*d+1] - hi16(p));
  }
  A = as_h8(ua); B = as_h8(ub);
}

__global__ void __launch_bounds__(NTHR, 1)
lstm_mfma(const float* __restrict__ x, const unsigned* __restrict__ xp, int use_xp,
          const float* __restrict__ Wih0, const float* __restrict__ bih0,
          const float* __restrict__ Whh0, const float* __restrict__ bhh0,
          const float* __restrict__ Wih1, const float* __restrict__ bih1,
          const float* __restrict__ Whh1, const float* __restrict__ bhh1,
          unsigned* h1p, unsigned* h2p,
          unsigned* sync, float* out)
{
  __shared__ v4u ls1[2 * NKT * 64];   // 49152 B: L1 lo-plane (2 n-tiles)
  __shared__ int sh_r;

  const int tid   = threadIdx.x;
  const int lane  = tid & 63;
  const int mt    = tid >> 6;          // wave id
  const int n     = lane & 15;
  const int quad  = lane >> 4;
  const int bl    = n & 7;             // A-row -> local batch (rows 8-15 dup, discarded)
  const unsigned g = xccid();          // group = physical XCD

  unsigned* flg   = sync;              // 8 groups x 64 (32 used, one line each)
  unsigned* cnt   = sync + 512;        // 8 rank counters
  unsigned* ready = sync + 520;        // rendezvous counter

  // ---- rank within XCD ----
  if (tid == 0)
    sh_r = (int)__hip_atomic_fetch_add(cnt + g, 1u, __ATOMIC_RELAXED, __HIP_MEMORY_SCOPE_AGENT);
  __syncthreads();
  const int r = sh_r;
  const bool work = (r < GW);          // pigeonhole: exactly 32/XCD -> always true
  const bool doL1w = work && (mt >= 2);
  const int tt = mt - 2;               // L1 n-tile for waves 2,3

  // ---- startup: clear stale cross-launch L2, then MALL rendezvous ----
  acq_fence();
  if (tid == 0)
    __hip_atomic_fetch_add(ready, 1u, __ATOMIC_RELAXED, __HIP_MEMORY_SCOPE_AGENT);

  // ---- prologue: pack weights (overlaps others' rendezvous) ----
  // L0: wave mt owns n-tile mt of h1-cols [16r,16r+16): gcol0 in [0,2048)
  // L1: waves 2,3 own n-tiles of h2-cols [8r,8r+8):     gcol1 in [0,1024)
  v4u wfa0[NKT], wfb0[NKT], wfa1[NKT];
  float bsum0 = 0.f, bsum1 = 0.f;
  if (work){
    const int gcol0 = (n >> 2) * H0 + r * 16 + mt * 4 + (n & 3);
    #pragma unroll
    for (int kt = 0; kt < NKT; ++kt){
      const int ks = kt * 32 + quad * 8;
      float w[8];
      #pragma unroll
      for (int j = 0; j < 8; ++j){
        const int k = ks + j;
        w[j] = (k < DIN) ? Wih0[(size_t)k * (4*H0) + gcol0]
                         : Whh0[(size_t)(k - DIN) * (4*H0) + gcol0];
      }
      #pragma unroll
      for (int d = 0; d < 4; ++d){
        const unsigned p = pk2(w[2*d], w[2*d+1]);
        wfa0[kt][d] = p;
        wfb0[kt][d] = pk2(w[2*d] - lo16(p), w[2*d+1] - hi16(p));
      }
    }
    bsum0 = bih0[gcol0] + bhh0[gcol0];
    if (mt >= 2){
      const int gcol1 = (n >> 2) * H1 + r * 8 + tt * 4 + (n & 3);
      #pragma unroll
      for (int kt = 0; kt < NKT; ++kt){
        const int ks = kt * 32 + quad * 8;
        float w[8];
        #pragma unroll
        for (int j = 0; j < 8; ++j){
          const int k = ks + j;
          w[j] = (k < H0) ? Wih1[(size_t)k * (4*H1) + gcol1]
                          : Whh1[(size_t)(k - H0) * (4*H1) + gcol1];
        }
        v4u ub;
        #pragma unroll
        for (int d = 0; d < 4; ++d){
          const unsigned p = pk2(w[2*d], w[2*d+1]);
          wfa1[kt][d] = p;
          ub[d] = pk2(w[2*d] - lo16(p), w[2*d+1] - hi16(p));
        }
        ls1[(tt * NKT + kt) * 64 + lane] = ub;
      }
      bsum1 = bih1[gcol1] + bhh1[gcol1];
    }
  }

  // ---- rendezvous: all 256 WGs fenced before any L2-local store ----
  if (tid == 0){
    for (int it = 0; it < (1 << 22); ++it){
      if (__hip_atomic_load(ready, __ATOMIC_RELAXED, __HIP_MEMORY_SCOPE_AGENT) >= NWG) break;
      __builtin_amdgcn_s_sleep(2);
    }
  }
  __syncthreads();
  if (!work) return;

  unsigned* h1g = h1p + (size_t)g * (2 * 8 * H0);
  unsigned* h2g = h2p + (size_t)g * (2 * 8 * H1);
  const unsigned* flgg = flg + (size_t)g * 64;

  float c0=0.f,c1=0.f,c2=0.f,c3=0.f;      // L0 cell state (lanes n<4, quad<2)
  float d0=0.f,d1=0.f,d2=0.f,d3=0.f;      // L1 cell state (waves 2,3)

  // iteration i: compute h1(i) (i<TT) and h2(i-1) (i>=1)
  for (int i = 0; i <= TT; ++i){
    const bool doL0 = (i < TT);
    const bool doL1 = (i >= 1) && (mt >= 2);

    v4f a0a = { bsum0, bsum0, bsum0, bsum0 };
    v4f a0b = { 0.f, 0.f, 0.f, 0.f };
    v4f a1a = { bsum1, bsum1, bsum1, bsum1 };
    v4f a1b = { 0.f, 0.f, 0.f, 0.f };

    // ---- x-part: immutable input, runs before the wait ----
    if (doL0){
      if (use_xp){
        const unsigned* xr = xp + ((size_t)(8*g + bl) * TT + i) * DIN + quad * 8;
        #pragma unroll
        for (int kt = 0; kt < 8; ++kt){
          v4u p0 = *(const v4u*)(xr + kt * 32);
          v4u p1 = *(const v4u*)(xr + kt * 32 + 4);
          v8h A, Ab; frag_from_pairs(p0, p1, A, Ab);
          v8h Wa = as_h8(wfa0[kt]), Wb = as_h8(wfb0[kt]);
          a0a = mfma16(A,  Wa, a0a);
          a0b = mfma16(A,  Wb, a0b);
          a0b = mfma16(Ab, Wa, a0b);
        }
      } else {
        const float* xr = x + ((size_t)(8*g + bl) * TT + i) * DIN + quad * 8;
        #pragma unroll
        for (int kt = 0; kt < 8; ++kt){
          v4f f0 = *(const v4f*)(xr + kt * 32);
          v4f f1 = *(const v4f*)(xr + kt * 32 + 4);
          v8h A, Ab; frag_from_floats(f0, f1, A, Ab);
          v8h Wa = as_h8(wfa0[kt]), Wb = as_h8(wfb0[kt]);
          a0a = mfma16(A,  Wa, a0a);
          a0b = mfma16(A,  Wb, a0b);
          a0b = mfma16(Ab, Wa, a0b);
        }
      }
    }

    // ---- the single per-step wait (L2-local), then L1-only invalidate ----
    if (i >= 1) waitflags(flgg, (unsigned)i, lane);
    inv_l1();

    // ---- h1(i-1) A-frags feed BOTH layers (same slot (i+1)&1 == (i-1)&1) ----
    {
      const unsigned* hr = h1g + (size_t)((i + 1) & 1) * (8 * H0) + (size_t)bl * H0 + quad * 8;
      #pragma unroll
      for (int kt = 0; kt < 16; ++kt){
        v4u p0 = *(const v4u*)(hr + kt * 32);
        v4u p1 = *(const v4u*)(hr + kt * 32 + 4);
        v8h A, Ab; frag_from_pairs(p0, p1, A, Ab);
        if (doL0){
          v8h Wa = as_h8(wfa0[kt + 8]), Wb = as_h8(wfb0[kt + 8]);
          a0a = mfma16(A,  Wa, a0a);
          a0b = mfma16(A,  Wb, a0b);
          a0b = mfma16(Ab, Wa, a0b);
        }
        if (doL1){
          v8h Wa = as_h8(wfa1[kt]), Wb = as_h8(ls1[(tt * NKT + kt) * 64 + lane]);
          a1a = mfma16(A,  Wa, a1a);
          a1b = mfma16(A,  Wb, a1b);
          a1b = mfma16(Ab, Wa, a1b);
        }
      }
    }
    // ---- h2(i-2) part (slot i&1) ----
    if (doL1){
      const unsigned* hr = h2g + (size_t)(i & 1) * (8 * H1) + (size_t)bl * H1 + quad * 8;
      #pragma unroll
      for (int kt = 0; kt < 8; ++kt){
        v4u p0 = *(const v4u*)(hr + kt * 32);
        v4u p1 = *(const v4u*)(hr + kt * 32 + 4);
        v8h A, Ab; frag_from_pairs(p0, p1, A, Ab);
        v8h Wa = as_h8(wfa1[kt + 16]), Wb = as_h8(ls1[(tt * NKT + 16 + kt) * 64 + lane]);
        a1a = mfma16(A,  Wa, a1a);
        a1b = mfma16(A,  Wb, a1b);
        a1b = mfma16(Ab, Wa, a1b);
      }
    }

    // ---- EW L0: 4 h-cols x 8 batches per wave; plain stores (dirty L2) ----
    if (doL0){
      v4f gv = a0a + a0b;
      float pv0 = __shfl_xor(gv[0], 4), pv1 = __shfl_xor(gv[1], 4),
            pv2 = __shfl_xor(gv[2], 4), pv3 = __shfl_xor(gv[3], 4);
      float qv0 = __shfl_xor(gv[0], 8), qv1 = __shfl_xor(gv[1], 8),
            qv2 = __shfl_xor(gv[2], 8), qv3 = __shfl_xor(gv[3], 8);
      float sv0 = __shfl_xor(pv0, 8), sv1 = __shfl_xor(pv1, 8),
            sv2 = __shfl_xor(pv2, 8), sv3 = __shfl_xor(pv3, 8);
      if (n < 4 && quad < 2){
        float iv[4] = { gv[0], gv[1], gv[2], gv[3] };
        float fv[4] = { pv0, pv1, pv2, pv3 };
        float gg[4] = { qv0, qv1, qv2, qv3 };
        float ov[4] = { sv0, sv1, sv2, sv3 };
        float cc[4] = { c0, c1, c2, c3 };
        const int col = r * 16 + mt * 4 + n;
        unsigned* hb = h1g + (size_t)(i & 1) * (8 * H0) + col;
        #pragma unroll
        for (int rr = 0; rr < 4; ++rr){
          float cn = sigf(fv[rr]) * cc[rr] + sigf(iv[rr]) * tanhf_(gg[rr]);
          float hn = sigf(ov[rr]) * tanhf_(cn);
          cc[rr] = cn;
          unsigned pa = pk2(hn, 0.f);
          hb[(size_t)(quad * 4 + rr) * H0] = pk2(hn, hn - lo16(pa));
        }
        c0 = cc[0]; c1 = cc[1]; c2 = cc[2]; c3 = cc[3];
      }
    }
    // ---- EW L1 (waves 2,3): h2 + out ----
    if (doL1){
      v4f gv = a1a + a1b;
      float pv0 = __shfl_xor(gv[0], 4), pv1 = __shfl_xor(gv[1], 4),
            pv2 = __shfl_xor(gv[2], 4), pv3 = __shfl_xor(gv[3], 4);
      float qv0 = __shfl_xor(gv[0], 8), qv1 = __shfl_xor(gv[1], 8),
            qv2 = __shfl_xor(gv[2], 8), qv3 = __shfl_xor(gv[3], 8);
      float sv0 = __shfl_xor(pv0, 8), sv1 = __shfl_xor(pv1, 8),
            sv2 = __shfl_xor(pv2, 8), sv3 = __shfl_xor(pv3, 8);
      if (n < 4 && quad < 2){
        float iv[4] = { gv[0], gv[1], gv[2], gv[3] };
        float fv[4] = { pv0, pv1, pv2, pv3 };
        float gg[4] = { qv0, qv1, qv2, qv3 };
        float ov[4] = { sv0, sv1, sv2, sv3 };
        float cc[4] = { d0, d1, d2, d3 };
        const int col = r * 8 + tt * 4 + n;
        const int t1  = i - 1;
        unsigned* hb = h2g + (size_t)(t1 & 1) * (8 * H1) + col;
        #pragma unroll
        for (int rr = 0; rr < 4; ++rr){
          float cn = sigf(fv[rr]) * cc[rr] + sigf(iv[rr]) * tanhf_(gg[rr]);
          float hn = sigf(ov[rr]) * tanhf_(cn);
          cc[rr] = cn;
          const int b_ = quad * 4 + rr;
          unsigned pa = pk2(hn, 0.f);
          hb[(size_t)b_ * H1] = pk2(hn, hn - lo16(pa));
          // out must survive any future invalidation: write-through to MALL
          __hip_atomic_store(out + ((size_t)(8*g + b_) * TT + t1) * H1 + col, hn,
                             __ATOMIC_RELAXED, __HIP_MEMORY_SCOPE_AGENT);
        }
        d0 = cc[0]; d1 = cc[1]; d2 = cc[2]; d3 = cc[3];
      }
    }

    // ---- publish: barrier drains vmcnt (stores are in the shared L2) ->
    //      plain flag store into the group's flag line ----
    __syncthreads();
    if (tid == 0)
      ((volatile unsigned*)flgg)[r] = (unsigned)(i + 1);
  }
}

__global__ void init_ws(unsigned* ws, int nz){
  int i = blockIdx.x * blockDim.x + threadIdx.x;
  if (i < nz)
    __hip_atomic_store(ws + i, 0u, __ATOMIC_RELAXED, __HIP_MEMORY_SCOPE_AGENT);
}

__global__ void conv_x(const float4* __restrict__ x4,
                       unsigned long long* __restrict__ xp2, int n4){
  int i = blockIdx.x * blockDim.x + threadIdx.x;
  if (i >= n4) return;
  float4 f = x4[i];
  float v[4] = { f.x, f.y, f.z, f.w };
  unsigned o[4];
  #pragma unroll
  for (int d = 0; d < 4; ++d){
    unsigned p = pk2(v[d], 0.f);
    o[d] = pk2(v[d], v[d] - lo16(p));
  }
  unsigned long long lo = (unsigned long long)o[0] | ((unsigned long long)o[1] << 32);
  unsigned long long hi = (unsigned long long)o[2] | ((unsigned long long)o[3] << 32);
  __hip_atomic_store(xp2 + 2 * i + 0, lo, __ATOMIC_RELAXED, __HIP_MEMORY_SCOPE_AGENT);
  __hip_atomic_store(xp2 + 2 * i + 1, hi, __ATOMIC_RELAXED, __HIP_MEMORY_SCOPE_AGENT);
}

extern "C" void kernel_launch(void* const* d_in, const int* in_sizes, int n_in,
                              void* d_out, int out_size, void* d_ws, size_t ws_size,
                              hipStream_t stream) {
  const float* x    = (const float*)d_in[0];
  const float* Wih0 = (const float*)d_in[1];
  const float* bih0 = (const float*)d_in[2];
  const float* Whh0 = (const float*)d_in[3];
  const float* bhh0 = (const float*)d_in[4];
  const float* Wih1 = (const float*)d_in[5];
  const float* bih1 = (const float*)d_in[6];
  const float* Whh1 = (const float*)d_in[7];
  const float* bhh1 = (const float*)d_in[8];
  float* outp = (float*)d_out;

  unsigned* ws   = (unsigned*)d_ws;
  unsigned* h1p  = ws;                       // 8 groups x 2 slots x 8 x 512 = 65536
  unsigned* h2p  = h1p + 8 * 2 * 8 * H0;     // 8 x 2 x 8 x 256 = 32768
  unsigned* sync = h2p + 8 * 2 * 8 * H1;     // flg 512 + cnt 8 + ready 8 = 528
  unsigned* xp   = sync + 528;               // optional: B*T*DIN pair dwords
  const int nz = 8*2*8*H0 + 8*2*8*H1 + 528;  // 98832 dwords to zero

  const size_t need_xp = ((size_t)nz + (size_t)BB * TT * DIN) * 4;
  int use_xp = (ws_size >= need_xp) ? 1 : 0;

  init_ws<<<dim3((nz + 255) / 256), dim3(256), 0, stream>>>(ws, nz);
  if (use_xp){
    const int n4 = BB * TT * DIN / 4;
    conv_x<<<dim3((n4 + 255) / 256), dim3(256), 0, stream>>>(
        (const float4*)x, (unsigned long long*)xp, n4);
  }

  lstm_mfma<<<dim3(NWG), dim3(NTHR), 0, stream>>>(
      x, xp, use_xp,
      Wih0, bih0, Whh0, bhh0,
      Wih1, bih1, Whh1, bhh1,
      h1p, h2p, sync, outp);
}